// Round 14
// baseline (154.076 us; speedup 1.0000x reference)
//
#include <hip/hip_runtime.h>
#include <hip/hip_bf16.h>
#include <math.h>

#define J 25
#define NJC 75             // J * CIN
#define NWAVE 4            // waves per block
#define NTHREADS 256
#define NFPW 4             // frames per wave
#define SCRW 1056          // per-wave scratch: 4 blocks x 264 bf16 (X staging ONLY)

// const-image layout (bf16 element offsets in ws)
#define O_A1T  0           // B for P1, natural k=j, 1024
#define O_APP  1024        // B for P4, k32-permuted, 1024
#define O_A4B  2048        // A for P7, k32-permuted, 1024
#define O_W2T  3072        // B for P3, k64-permuted, 2048
#define O_W3T  5120        // A for P5, k32-permuted, 2 M-tiles, 2048
#define O_W1T  7168        // A for P2, padded [tt][half][m][c8], half1=0, 1024
#define O_W4C  8192        // B for P6, k64-permuted, [c][b][j], 256
#define O_B4   8512        // 4 floats (8 bf16 slots)
#define O_BPPF 8576        // 64 fp32 bias in C-reg order [q(4)][half(2)][jj(8)]

using bf16x8 = __attribute__((ext_vector_type(8))) __bf16;
using f32x4  = __attribute__((ext_vector_type(4))) float;
using f32x16 = __attribute__((ext_vector_type(16))) float;

__device__ inline bf16x8 zero8() {
    bf16x8 z;
    #pragma unroll
    for (int j = 0; j < 8; j++) z[j] = (__bf16)0.f;
    return z;
}

// packed f32 pair -> bf16 pair (v_cvt_pk_bf16_f32 on gfx950)
__device__ inline unsigned pk2(float a, float b) {
    float2 f2; f2.x = a; f2.y = b;
    __hip_bfloat162 h = __float22bfloat162_rn(f2);
    union { __hip_bfloat162 h2; unsigned u; } cv; cv.h2 = h;
    return cv.u;
}
__device__ inline bf16x8 mk8(unsigned a, unsigned b, unsigned c, unsigned d) {
    union { uint4 u4; bf16x8 v; } cv;
    cv.u4.x = a; cv.u4.y = b; cv.u4.z = c; cv.u4.w = d;
    return cv.v;
}
// pack 8 consecutive acc elements (base = 8*st) into one operand frag
__device__ inline bf16x8 pk8(const f32x16& acc, int st) {
    const int b = 8 * st;
    return mk8(pk2(acc[b],     acc[b + 1]), pk2(acc[b + 2], acc[b + 3]),
               pk2(acc[b + 4], acc[b + 5]), pk2(acc[b + 6], acc[b + 7]));
}

// ---------------------------------------------------------------------------
// K-permutations (match between tables and producer packing):
//   C-ladder: rho(r,h) = (r&3) + 8*(r>>2) + 4*h
//   K=32: d32(s,h,j) = rho(8*s+j, h);  K=64: d64(s,h,j) = 32*(s>>1)+rho(8*(s&1)+j,h)
// Producer C -> operand verbatim: op[s][j] = acc[8*s+j].
// ---------------------------------------------------------------------------

// ---------------------------------------------------------------------------
// Precompute (1 block, 256 thr): softmax(A1..A4), App=A3s@A2s, bpp=W3^T b2+b3,
// then emit bf16 frag tables with K-permutations baked in + fp32 bias table.
// ---------------------------------------------------------------------------
__global__ void gcn_precompute(
    const float* __restrict__ A1, const float* __restrict__ W1, const float* __restrict__ b1,
    const float* __restrict__ A2, const float* __restrict__ W2, const float* __restrict__ b2,
    const float* __restrict__ A3, const float* __restrict__ W3, const float* __restrict__ b3,
    const float* __restrict__ A4, const float* __restrict__ W4, const float* __restrict__ b4,
    __bf16* __restrict__ cw)
{
    __shared__ float T[3125];      // T0..T3 softmax(A1..A4), T4 = App
    __shared__ float bpp[64];
    float* T0 = T;        float* T1 = T + 625;  float* T2 = T + 1250;
    float* T3 = T + 1875; float* T4 = T + 2500;
    const int t = threadIdx.x;

    if (t < 100) {
        const int m = t / J, i = t % J;
        const float* Asrc = (m == 0) ? A1 : (m == 1) ? A2 : (m == 2) ? A3 : A4;
        float row[J];
        float mx = -1e30f;
        #pragma unroll
        for (int j = 0; j < J; j++) { row[j] = Asrc[i * J + j]; mx = fmaxf(mx, row[j]); }
        float s = 0.f;
        #pragma unroll
        for (int j = 0; j < J; j++) { row[j] = __expf(row[j] - mx); s += row[j]; }
        const float inv = 1.f / s;
        float* dst = T + m * 625 + i * J;
        #pragma unroll
        for (int j = 0; j < J; j++) dst[j] = row[j] * inv;
    }
    if (t < 64) {                                      // bpp = W3^T b2 + b3
        float s = b3[t];
        #pragma unroll
        for (int l = 0; l < 32; l++) s += W3[l * 64 + t] * b2[l];
        bpp[t] = s;
    }
    __syncthreads();

    for (int idx = t; idx < 625; idx += 256) {        // App = A3s @ A2s
        const int i = idx / J, jj = idx % J;
        float s = 0.f;
        #pragma unroll
        for (int k = 0; k < J; k++) s += T2[i * J + k] * T1[k * J + jj];
        T4[idx] = s;
    }
    __syncthreads();

    // ---- A1T (natural k) | App, A4b (k32-permuted) ----
    for (int i = t; i < 1024; i += 256) {
        const int b = i >> 8, n = (i >> 3) & 31, jj = i & 7;
        const int kn = 8 * b + jj;                                  // natural
        cw[O_A1T + i] = (__bf16)((kn < J && n < J) ? T0[n * J + kn] : 0.f);
        const int s = b >> 1, h = b & 1, r = 8 * s + jj;            // s in 0..1
        const int k32 = (r & 3) + 8 * (r >> 2) + 4 * h;
        cw[O_APP + i] = (__bf16)((k32 < J && n < J) ? T4[n * J + k32] : 0.f);
        cw[O_A4B + i] = (__bf16)((k32 < J && n < J) ? T3[n * J + k32] : 0.f);
    }
    // ---- W2T (k64-perm) | W3T (k32-perm, 2 tiles) ----
    for (int i = t; i < 2048; i += 256) {
        {   // W2T: (b, n=l, j) = W2[d64][l]
            const int b = i >> 8, n = (i >> 3) & 31, jj = i & 7;
            const int s = b >> 1, h = b & 1, r = 8 * (s & 1) + jj;
            const int d = 32 * (s >> 1) + (r & 3) + 8 * (r >> 2) + 4 * h;
            cw[O_W2T + i] = (__bf16)W2[d * 32 + n];
        }
        {   // W3T: (tt, b, m, j) = W3[l=d32][tt*32+m]
            const int tt = i >> 10, rr = i & 1023;
            const int b = rr >> 8, m = (rr >> 3) & 31, jj = rr & 7;
            const int s = b >> 1, h = b & 1, r = 8 * s + jj;
            const int l = (r & 3) + 8 * (r >> 2) + 4 * h;
            cw[O_W3T + i] = (__bf16)W3[l * 64 + tt * 32 + m];
        }
    }
    // ---- W1T (padded, half1=0, b1 in c=3) ----
    for (int i = t; i < 1024; i += 256) {
        const int tt = i >> 9, r = i & 511, hf = r >> 8, q = r & 255;
        const int m = q >> 3, c = q & 7, d = tt * 32 + m;
        float v = 0.f;
        if (hf == 0) {
            if (c < 3) v = W1[c * 64 + d];
            else if (c == 3) v = b1[d];
        }
        cw[O_W1T + i] = (__bf16)v;
    }
    // ---- W4c (k64-perm): [c][b][j] = W4[d64][c] ----
    if (t < 256) {
        const int c = t >> 6, b = (t >> 3) & 7, jj = t & 7;
        const int s = b >> 1, h = b & 1, r = 8 * (s & 1) + jj;
        const int d = 32 * (s >> 1) + (r & 3) + 8 * (r >> 2) + 4 * h;
        cw[O_W4C + t] = (c < 3) ? (__bf16)W4[d * 3 + c] : (__bf16)0.f;
    }
    // ---- fp32 bias table, C-reg order: [q=2tt+st][half][jj] ----
    {
        float* fwB = (float*)(cw + O_BPPF);
        if (t < 64) {
            const int q = t >> 4, h = (t >> 3) & 1, jj = t & 7;
            const int tt = q >> 1, st = q & 1;
            const int row32 = (jj & 3) + 16 * st + 8 * (jj >> 2) + 4 * h;
            fwB[t] = bpp[tt * 32 + row32];
        }
    }
    float* fb4 = (float*)(cw + O_B4);
    if (t >= 64 && t < 68) fb4[t - 64] = (t < 67) ? b4[t - 64] : 0.f;
}

// ---------------------------------------------------------------------------
// Fused kernel — register-direct pipeline (R13 structure) with packed bf16
// conversions (v_cvt_pk_bf16_f32 via __float22bfloat162_rn) and fp32-resident
// bias. LDS only stages X; ones-row & K-pads written once (X blocks never
// overwritten). Zero barriers; per-wave DS in-order.
//
// mfma_f32_32x32x16_bf16 (verified): A[m][k]: m=lane&31, k=8*(lane>>5)+j+16ks
//   B[k][n]: n=lane&31, same k.  C/D: col(lane)=n, rows = ladder rho.
// ---------------------------------------------------------------------------
__global__ __launch_bounds__(NTHREADS, 2) void gcn_fused(
    const float* __restrict__ x,
    const __bf16* __restrict__ cw,
    float* __restrict__ out)
{
    __shared__ __align__(16) __bf16 SCR[NWAVE * SCRW];

    const int t = threadIdx.x;
    const int w = t >> 6, lane = t & 63, ln = lane & 31, half = lane >> 5;
    const int fo = ln * 8;
    __bf16* sc = &SCR[w * SCRW];

    const long fbase = ((long)blockIdx.x * NWAVE + w) * NFPW;

    // ---- first-frame x prefetch
    long xb = fbase * NJC;
    float xv0 = x[xb + lane];
    float xv1 = (lane < NJC - 64) ? x[xb + 64 + lane] : 0.f;

    // ---- one-time X-region constants (blocks 0-3 are X-only)
    if (half == 0) sc[(ln >> 3) * 264 + 24 + (ln & 7)] = (ln < J) ? (__bf16)1.f : (__bf16)0.f;
    if (lane < 21) sc[3 * 264 + (lane / 7) * 8 + 1 + (lane % 7)] = (__bf16)0.f;

    // ---- register frag loads (once per wave, from L2-hot ws image)
    bf16x8 rA1T[2], rApp[2], rA4b[2], rW1[2], rW2[4], rW3[4], rW4[4];
    #pragma unroll
    for (int ks = 0; ks < 2; ks++) {
        rA1T[ks] = *(const bf16x8*)&cw[O_A1T + (2 * ks + half) * 256 + fo];
        rApp[ks] = *(const bf16x8*)&cw[O_APP + (2 * ks + half) * 256 + fo];
        rA4b[ks] = *(const bf16x8*)&cw[O_A4B + (2 * ks + half) * 256 + fo];
        rW1[ks]  = *(const bf16x8*)&cw[O_W1T + ks * 512 + half * 256 + fo];
    }
    #pragma unroll
    for (int ks = 0; ks < 4; ks++)
        rW2[ks] = *(const bf16x8*)&cw[O_W2T + (half + 2 * ks) * 256 + fo];
    #pragma unroll
    for (int tt = 0; tt < 2; tt++)
        #pragma unroll
        for (int ks = 0; ks < 2; ks++)
            rW3[tt * 2 + ks] = *(const bf16x8*)&cw[O_W3T + tt * 1024 + (half + 2 * ks) * 256 + fo];
    #pragma unroll
    for (int ks = 0; ks < 4; ks++) {
        rW4[ks] = zero8();
        if (ln < 3) rW4[ks] = *(const bf16x8*)&cw[O_W4C + ln * 64 + (half + 2 * ks) * 8];
    }
    // fp32 bias, C-reg order: rBq[q*2+p] = float4 at [q][half][4p]
    f32x4 rBq[8];
    {
        const float* fwB = (const float*)(cw + O_BPPF);
        #pragma unroll
        for (int q = 0; q < 4; q++)
            #pragma unroll
            for (int p = 0; p < 2; p++)
                rBq[q * 2 + p] = *(const f32x4*)&fwB[(q * 2 + half) * 8 + 4 * p];
    }
    float b4v = 0.f;
    if (ln < 3) b4v = ((const float*)(cw + O_B4))[ln];

    // ---- shared zero accumulator (MFMA allows D != C)
    f32x16 Z;
    #pragma unroll
    for (int z = 0; z < 16; z++) Z[z] = 0.f;

    // X scatter coords: element i -> A[c=i%3][k=i/3]
    const int c0 = lane % 3, j0 = lane / 3;
    const int sc0 = (j0 >> 3) * 264 + c0 * 8 + (j0 & 7);
    const int i1 = 64 + lane, c1 = i1 % 3, j1 = i1 / 3;
    const int sc1 = (j1 >> 3) * 264 + c1 * 8 + (j1 & 7);

    for (int fi = 0; fi < NFPW; fi++) {
        const long f = fbase + fi;

        // ---- X staging (only per-frame LDS writes)
        sc[sc0] = (__bf16)xv0;
        if (lane < NJC - 64) sc[sc1] = (__bf16)xv1;

        // ---- prefetch next frame's x
        float nxv0 = 0.f, nxv1 = 0.f;
        if (fi + 1 < NFPW) {
            const long nxb = (f + 1) * NJC;
            nxv0 = x[nxb + lane];
            if (lane < NJC - 64) nxv1 = x[nxb + 64 + lane];
        }

        // ---- P1: Y^T = Xaug^T @ A1T  (A from LDS, natural k)
        bf16x8 a0 = *(const bf16x8*)&sc[half * 264 + fo];
        bf16x8 a1 = *(const bf16x8*)&sc[(2 + half) * 264 + fo];
        f32x16 accY = __builtin_amdgcn_mfma_f32_32x32x16_bf16(a0, rA1T[0], Z, 0, 0, 0);
        accY = __builtin_amdgcn_mfma_f32_32x32x16_bf16(a1, rA1T[1], accY, 0, 0, 0);

        // ---- P2: H^T = relu(W1 @ Y^T); Y in-register; pack C -> K64 A-frag
        bf16x8 yb;
        #pragma unroll
        for (int jj = 0; jj < 8; jj++)
            yb[jj] = (half == 0 && jj < 4) ? (__bf16)accY[jj] : (__bf16)0.f;
        bf16x8 hf[4];
        #pragma unroll
        for (int tt = 0; tt < 2; tt++) {
            f32x16 acc = __builtin_amdgcn_mfma_f32_32x32x16_bf16(rW1[tt], yb, Z, 0, 0, 0);
            #pragma unroll
            for (int z = 0; z < 16; z++) acc[z] = fmaxf(acc[z], 0.f);
            hf[2 * tt]     = pk8(acc, 0);
            hf[2 * tt + 1] = pk8(acc, 1);
        }

        // ---- P3: U = H @ W2  (K=64) -> C lane=l, rows=i
        f32x16 accU = __builtin_amdgcn_mfma_f32_32x32x16_bf16(hf[0], rW2[0], Z, 0, 0, 0);
        #pragma unroll
        for (int s = 1; s < 4; s++)
            accU = __builtin_amdgcn_mfma_f32_32x32x16_bf16(hf[s], rW2[s], accU, 0, 0, 0);
        bf16x8 uf[2] = { pk8(accU, 0), pk8(accU, 1) };

        // ---- P4: V = App @ U -> lane=i', rows=l
        f32x16 accV = __builtin_amdgcn_mfma_f32_32x32x16_bf16(uf[0], rApp[0], Z, 0, 0, 0);
        accV = __builtin_amdgcn_mfma_f32_32x32x16_bf16(uf[1], rApp[1], accV, 0, 0, 0);
        bf16x8 vf[2] = { pk8(accV, 0), pk8(accV, 1) };

        // ---- P5: HD^T = relu(W3 @ V^T + bpp) -> lane=i', rows=d
        bf16x8 hd[4];
        #pragma unroll
        for (int tt = 0; tt < 2; tt++) {
            f32x16 acc = __builtin_amdgcn_mfma_f32_32x32x16_bf16(rW3[tt * 2 + 0], vf[0], Z, 0, 0, 0);
            acc = __builtin_amdgcn_mfma_f32_32x32x16_bf16(rW3[tt * 2 + 1], vf[1], acc, 0, 0, 0);
            #pragma unroll
            for (int st = 0; st < 2; st++) {
                const int q = 2 * tt + st;
                #pragma unroll
                for (int jj = 0; jj < 8; jj++)
                    acc[8 * st + jj] = fmaxf(acc[8 * st + jj] + rBq[q * 2 + (jj >> 2)][jj & 3], 0.f);
                hd[q] = pk8(acc, st);
            }
        }

        // ---- P6: P = HD @ W4  (K=64) -> C lane=c, rows=i'
        f32x16 accP = __builtin_amdgcn_mfma_f32_32x32x16_bf16(hd[0], rW4[0], Z, 0, 0, 0);
        #pragma unroll
        for (int s = 1; s < 4; s++)
            accP = __builtin_amdgcn_mfma_f32_32x32x16_bf16(hd[s], rW4[s], accP, 0, 0, 0);
        bf16x8 pf[2] = { pk8(accP, 0), pk8(accP, 1) };

        // ---- P7: out = A4 @ P + b4 -> C lane=c, rows=i''
        f32x16 accO = __builtin_amdgcn_mfma_f32_32x32x16_bf16(rA4b[0], pf[0], Z, 0, 0, 0);
        accO = __builtin_amdgcn_mfma_f32_32x32x16_bf16(rA4b[1], pf[1], accO, 0, 0, 0);
        if (ln < 3) {
            const long ob = f * NJC;
            #pragma unroll
            for (int r = 0; r < 16; r++) {
                const int row = (r & 3) + 8 * (r >> 2) + 4 * half;
                if (row < J) out[ob + row * 3 + ln] = accO[r] + b4v;
            }
        }

        xv0 = nxv0; xv1 = nxv1;
    }
}

// ---------------------------------------------------------------------------
extern "C" void kernel_launch(void* const* d_in, const int* in_sizes, int n_in,
                              void* d_out, int out_size, void* d_ws, size_t ws_size,
                              hipStream_t stream)
{
    const float* x  = (const float*)d_in[0];
    const float* A1 = (const float*)d_in[1];
    const float* W1 = (const float*)d_in[2];
    const float* b1 = (const float*)d_in[3];
    const float* A2 = (const float*)d_in[4];
    const float* W2 = (const float*)d_in[5];
    const float* b2 = (const float*)d_in[6];
    const float* A3 = (const float*)d_in[7];
    const float* W3 = (const float*)d_in[8];
    const float* b3 = (const float*)d_in[9];
    const float* A4 = (const float*)d_in[10];
    const float* W4 = (const float*)d_in[11];
    const float* b4 = (const float*)d_in[12];
    float* out = (float*)d_out;
    __bf16* cw = (__bf16*)d_ws;

    const int NT = in_sizes[0] / NJC;                 // 65536
    const int nblocks = NT / (NWAVE * NFPW);          // 4096

    gcn_precompute<<<1, 256, 0, stream>>>(
        A1, W1, b1, A2, W2, b2, A3, W3, b3, A4, W4, b4, cw);
    gcn_fused<<<nblocks, NTHREADS, 0, stream>>>(x, cw, out);
}

// Round 15
// 145.273 us; speedup vs baseline: 1.0606x; 1.0606x over previous
//
#include <hip/hip_runtime.h>
#include <math.h>

#define J 25
#define NJC 75             // J * CIN
#define NWAVE 4            // waves per block
#define NTHREADS 256
#define NFPW 4             // frames per wave
#define SCRW 2112          // per-wave scratch: 2 X-regions x 4 blocks x 264 bf16

// const-image layout (bf16 element offsets in ws)
#define O_A1T  0           // B for P1, natural k=j, 1024
#define O_APP  1024        // B for P4, k32-permuted, 1024
#define O_A4B  2048        // A for P7, k32-permuted, 1024
#define O_W2T  3072        // B for P3, k64-permuted, 2048
#define O_W3T  5120        // A for P5, k32-permuted, 2 M-tiles, 2048
#define O_W1T  7168        // A for P2, padded [tt][half][m][c8], half1=0, 1024
#define O_W4C  8192        // B for P6, k64-permuted, [c][b][j], 256
#define O_B4   8512        // 4 floats (8 bf16 slots)
#define O_BPPF 8576        // 64 fp32 bias in C-reg order [g(4)][half(2)][jj(8)]

using bf16x2 = __attribute__((ext_vector_type(2))) __bf16;
using bf16x8 = __attribute__((ext_vector_type(8))) __bf16;
using f32x4  = __attribute__((ext_vector_type(4))) float;
using f32x16 = __attribute__((ext_vector_type(16))) float;

__device__ inline bf16x8 zero8() {
    bf16x8 z;
    #pragma unroll
    for (int j = 0; j < 8; j++) z[j] = (__bf16)0.f;
    return z;
}

// f32 pair -> bf16 pair. Native v_cvt_pk_bf16_f32 when the builtin exists;
// otherwise scalar casts (each lowers to a single cvt — R14 lesson: do NOT
// use __float22bfloat162_rn, it's a manual-rounding software path).
#if defined(__has_builtin)
#if __has_builtin(__builtin_amdgcn_cvt_pk_bf16_f32)
#define HAVE_PK_BF16 1
#endif
#endif

__device__ inline bf16x2 cvt2(float a, float b) {
#ifdef HAVE_PK_BF16
    return __builtin_amdgcn_cvt_pk_bf16_f32(a, b);
#else
    bf16x2 r; r[0] = (__bf16)a; r[1] = (__bf16)b; return r;
#endif
}
// pack 8 consecutive acc elements (base = 8*st) into one operand frag
__device__ inline bf16x8 pk8(const f32x16& acc, int st) {
    const int b = 8 * st;
    bf16x8 r;
    #pragma unroll
    for (int p = 0; p < 4; p++) {
        bf16x2 v = cvt2(acc[b + 2 * p], acc[b + 2 * p + 1]);
        r[2 * p] = v[0]; r[2 * p + 1] = v[1];
    }
    return r;
}

// ---------------------------------------------------------------------------
// K-permutations (match between tables and producer packing):
//   C-ladder: rho(r,h) = (r&3) + 8*(r>>2) + 4*h
//   K=32: d32(s,h,j) = rho(8*s+j, h);  K=64: d64(s,h,j) = 32*(s>>1)+rho(8*(s&1)+j,h)
// Producer C -> operand verbatim: op[s][j] = acc[8*s+j].
// ---------------------------------------------------------------------------

// ---------------------------------------------------------------------------
// Precompute (1 block, 256 thr): softmax(A1..A4), App=A3s@A2s, bpp=W3^T b2+b3,
// then emit bf16 frag tables with K-permutations baked in + fp32 bias table.
// ---------------------------------------------------------------------------
__global__ void gcn_precompute(
    const float* __restrict__ A1, const float* __restrict__ W1, const float* __restrict__ b1,
    const float* __restrict__ A2, const float* __restrict__ W2, const float* __restrict__ b2,
    const float* __restrict__ A3, const float* __restrict__ W3, const float* __restrict__ b3,
    const float* __restrict__ A4, const float* __restrict__ W4, const float* __restrict__ b4,
    __bf16* __restrict__ cw)
{
    __shared__ float T[3125];      // T0..T3 softmax(A1..A4), T4 = App
    __shared__ float bpp[64];
    float* T0 = T;        float* T1 = T + 625;  float* T2 = T + 1250;
    float* T3 = T + 1875; float* T4 = T + 2500;
    const int t = threadIdx.x;

    if (t < 100) {
        const int m = t / J, i = t % J;
        const float* Asrc = (m == 0) ? A1 : (m == 1) ? A2 : (m == 2) ? A3 : A4;
        float row[J];
        float mx = -1e30f;
        #pragma unroll
        for (int j = 0; j < J; j++) { row[j] = Asrc[i * J + j]; mx = fmaxf(mx, row[j]); }
        float s = 0.f;
        #pragma unroll
        for (int j = 0; j < J; j++) { row[j] = __expf(row[j] - mx); s += row[j]; }
        const float inv = 1.f / s;
        float* dst = T + m * 625 + i * J;
        #pragma unroll
        for (int j = 0; j < J; j++) dst[j] = row[j] * inv;
    }
    if (t < 64) {                                      // bpp = W3^T b2 + b3
        float s = b3[t];
        #pragma unroll
        for (int l = 0; l < 32; l++) s += W3[l * 64 + t] * b2[l];
        bpp[t] = s;
    }
    __syncthreads();

    for (int idx = t; idx < 625; idx += 256) {        // App = A3s @ A2s
        const int i = idx / J, jj = idx % J;
        float s = 0.f;
        #pragma unroll
        for (int k = 0; k < J; k++) s += T2[i * J + k] * T1[k * J + jj];
        T4[idx] = s;
    }
    __syncthreads();

    // ---- A1T (natural k) | App, A4b (k32-permuted) ----
    for (int i = t; i < 1024; i += 256) {
        const int b = i >> 8, n = (i >> 3) & 31, jj = i & 7;
        const int kn = 8 * b + jj;                                  // natural
        cw[O_A1T + i] = (__bf16)((kn < J && n < J) ? T0[n * J + kn] : 0.f);
        const int s = b >> 1, h = b & 1, r = 8 * s + jj;            // s in 0..1
        const int k32 = (r & 3) + 8 * (r >> 2) + 4 * h;
        cw[O_APP + i] = (__bf16)((k32 < J && n < J) ? T4[n * J + k32] : 0.f);
        cw[O_A4B + i] = (__bf16)((k32 < J && n < J) ? T3[n * J + k32] : 0.f);
    }
    // ---- W2T (k64-perm) | W3T (k32-perm, 2 tiles) ----
    for (int i = t; i < 2048; i += 256) {
        {   // W2T: (b, n=l, j) = W2[d64][l]
            const int b = i >> 8, n = (i >> 3) & 31, jj = i & 7;
            const int s = b >> 1, h = b & 1, r = 8 * (s & 1) + jj;
            const int d = 32 * (s >> 1) + (r & 3) + 8 * (r >> 2) + 4 * h;
            cw[O_W2T + i] = (__bf16)W2[d * 32 + n];
        }
        {   // W3T: (tt, b, m, j) = W3[l=d32][tt*32+m]
            const int tt = i >> 10, rr = i & 1023;
            const int b = rr >> 8, m = (rr >> 3) & 31, jj = rr & 7;
            const int s = b >> 1, h = b & 1, r = 8 * s + jj;
            const int l = (r & 3) + 8 * (r >> 2) + 4 * h;
            cw[O_W3T + i] = (__bf16)W3[l * 64 + tt * 32 + m];
        }
    }
    // ---- W1T (padded, half1=0, b1 in c=3) ----
    for (int i = t; i < 1024; i += 256) {
        const int tt = i >> 9, r = i & 511, hf = r >> 8, q = r & 255;
        const int m = q >> 3, c = q & 7, d = tt * 32 + m;
        float v = 0.f;
        if (hf == 0) {
            if (c < 3) v = W1[c * 64 + d];
            else if (c == 3) v = b1[d];
        }
        cw[O_W1T + i] = (__bf16)v;
    }
    // ---- W4c (k64-perm): [c][b][j] = W4[d64][c] ----
    if (t < 256) {
        const int c = t >> 6, b = (t >> 3) & 7, jj = t & 7;
        const int s = b >> 1, h = b & 1, r = 8 * (s & 1) + jj;
        const int d = 32 * (s >> 1) + (r & 3) + 8 * (r >> 2) + 4 * h;
        cw[O_W4C + t] = (c < 3) ? (__bf16)W4[d * 3 + c] : (__bf16)0.f;
    }
    // ---- fp32 bias table, C-reg order: [g=2tt+st][half][jj] ----
    {
        float* fwB = (float*)(cw + O_BPPF);
        if (t < 64) {
            const int g = t >> 4, h = (t >> 3) & 1, jj = t & 7;
            const int tt = g >> 1, st = g & 1;
            const int row32 = (jj & 3) + 16 * st + 8 * (jj >> 2) + 4 * h;
            fwB[t] = bpp[tt * 32 + row32];
        }
    }
    float* fb4 = (float*)(cw + O_B4);
    if (t >= 64 && t < 68) fb4[t - 64] = (t < 67) ? b4[t - 64] : 0.f;
}

// ---------------------------------------------------------------------------
// Fused kernel — register-direct pipeline (R13 structure), native packed
// bf16 converts, fp32-resident bias, and DOUBLE-BUFFERED X staging: the only
// LDS use is X, and frame f+1's writes go to the alternate region so they
// overlap frame f's compute (no same-address dependence). Ones-row & K-pads
// written once per region (X regions never overwritten). Zero barriers.
//
// mfma_f32_32x32x16_bf16 (verified): A[m][k]: m=lane&31, k=8*(lane>>5)+j+16ks
//   B[k][n]: n=lane&31, same k.  C/D: col(lane)=n, rows = ladder rho.
// ---------------------------------------------------------------------------
__global__ __launch_bounds__(NTHREADS, 2) void gcn_fused(
    const float* __restrict__ x,
    const __bf16* __restrict__ cw,
    float* __restrict__ out)
{
    __shared__ __align__(16) __bf16 SCR[NWAVE * SCRW];

    const int t = threadIdx.x;
    const int w = t >> 6, lane = t & 63, ln = lane & 31, half = lane >> 5;
    const int fo = ln * 8;
    __bf16* scr = &SCR[w * SCRW];       // two 1056-el X regions

    const long fbase = ((long)blockIdx.x * NWAVE + w) * NFPW;

    // ---- one-time X-region constants in BOTH regions
    #pragma unroll
    for (int r = 0; r < 2; r++) {
        __bf16* s = scr + r * 1056;
        if (half == 0) s[(ln >> 3) * 264 + 24 + (ln & 7)] = (ln < J) ? (__bf16)1.f : (__bf16)0.f;
        if (lane < 21) s[3 * 264 + (lane / 7) * 8 + 1 + (lane % 7)] = (__bf16)0.f;
    }

    // X scatter coords: element i -> A[c=i%3][k=i/3]
    const int c0 = lane % 3, j0 = lane / 3;
    const int sx0 = (j0 >> 3) * 264 + c0 * 8 + (j0 & 7);
    const int i1 = 64 + lane, c1 = i1 % 3, j1 = i1 / 3;
    const int sx1 = (j1 >> 3) * 264 + c1 * 8 + (j1 & 7);

    // ---- prologue: stage frame 0 into region 0; load frame 1 into regs
    {
        const long xb = fbase * NJC;
        float v0 = x[xb + lane];
        float v1 = (lane < NJC - 64) ? x[xb + 64 + lane] : 0.f;
        scr[sx0] = (__bf16)v0;
        if (lane < NJC - 64) scr[sx1] = (__bf16)v1;
    }
    float xv0 = 0.f, xv1 = 0.f;
    if (NFPW > 1) {
        const long xb = (fbase + 1) * NJC;
        xv0 = x[xb + lane];
        if (lane < NJC - 64) xv1 = x[xb + 64 + lane];
    }

    // ---- register frag loads (once per wave, from L2-hot ws image)
    bf16x8 rA1T[2], rApp[2], rA4b[2], rW1[2], rW2[4], rW3[4], rW4[4];
    #pragma unroll
    for (int ks = 0; ks < 2; ks++) {
        rA1T[ks] = *(const bf16x8*)&cw[O_A1T + (2 * ks + half) * 256 + fo];
        rApp[ks] = *(const bf16x8*)&cw[O_APP + (2 * ks + half) * 256 + fo];
        rA4b[ks] = *(const bf16x8*)&cw[O_A4B + (2 * ks + half) * 256 + fo];
        rW1[ks]  = *(const bf16x8*)&cw[O_W1T + ks * 512 + half * 256 + fo];
    }
    #pragma unroll
    for (int ks = 0; ks < 4; ks++)
        rW2[ks] = *(const bf16x8*)&cw[O_W2T + (half + 2 * ks) * 256 + fo];
    #pragma unroll
    for (int tt = 0; tt < 2; tt++)
        #pragma unroll
        for (int ks = 0; ks < 2; ks++)
            rW3[tt * 2 + ks] = *(const bf16x8*)&cw[O_W3T + tt * 1024 + (half + 2 * ks) * 256 + fo];
    #pragma unroll
    for (int ks = 0; ks < 4; ks++) {
        rW4[ks] = zero8();
        if (ln < 3) rW4[ks] = *(const bf16x8*)&cw[O_W4C + ln * 64 + (half + 2 * ks) * 8];
    }
    // fp32 bias, C-reg order: rBq[g*2+p] = float4 at [g][half][4p]
    f32x4 rBq[8];
    {
        const float* fwB = (const float*)(cw + O_BPPF);
        #pragma unroll
        for (int g = 0; g < 4; g++)
            #pragma unroll
            for (int p = 0; p < 2; p++)
                rBq[g * 2 + p] = *(const f32x4*)&fwB[(g * 2 + half) * 8 + 4 * p];
    }
    float b4v = 0.f;
    if (ln < 3) b4v = ((const float*)(cw + O_B4))[ln];

    // ---- shared zero accumulator (MFMA allows D != C)
    f32x16 Z;
    #pragma unroll
    for (int z = 0; z < 16; z++) Z[z] = 0.f;

    for (int fi = 0; fi < NFPW; fi++) {
        const long f = fbase + fi;
        __bf16* sc = scr + (fi & 1) * 1056;

        // ---- stage frame fi+1 into ALTERNATE region (overlaps this frame)
        if (fi + 1 < NFPW) {
            __bf16* sn = scr + ((fi + 1) & 1) * 1056;
            sn[sx0] = (__bf16)xv0;
            if (lane < NJC - 64) sn[sx1] = (__bf16)xv1;
        }
        // ---- prefetch frame fi+2's x
        if (fi + 2 < NFPW) {
            const long nxb = (f + 2) * NJC;
            xv0 = x[nxb + lane];
            if (lane < NJC - 64) xv1 = x[nxb + 64 + lane];
        }

        // ---- P1: Y^T = Xaug^T @ A1T  (A from LDS, natural k)
        bf16x8 a0 = *(const bf16x8*)&sc[half * 264 + fo];
        bf16x8 a1 = *(const bf16x8*)&sc[(2 + half) * 264 + fo];
        f32x16 accY = __builtin_amdgcn_mfma_f32_32x32x16_bf16(a0, rA1T[0], Z, 0, 0, 0);
        accY = __builtin_amdgcn_mfma_f32_32x32x16_bf16(a1, rA1T[1], accY, 0, 0, 0);

        // ---- P2: H^T = relu(W1 @ Y^T); Y in-register (half0 regs 0-3 = k 0-3)
        bf16x8 yb = zero8();
        if (half == 0) {
            bf16x2 q0 = cvt2(accY[0], accY[1]);
            bf16x2 q1 = cvt2(accY[2], accY[3]);
            yb[0] = q0[0]; yb[1] = q0[1]; yb[2] = q1[0]; yb[3] = q1[1];
        }
        bf16x8 hf[4];
        #pragma unroll
        for (int tt = 0; tt < 2; tt++) {
            f32x16 acc = __builtin_amdgcn_mfma_f32_32x32x16_bf16(rW1[tt], yb, Z, 0, 0, 0);
            #pragma unroll
            for (int z = 0; z < 16; z++) acc[z] = fmaxf(acc[z], 0.f);
            hf[2 * tt]     = pk8(acc, 0);
            hf[2 * tt + 1] = pk8(acc, 1);
        }

        // ---- P3: U = H @ W2  (K=64) -> C lane=l, rows=i
        f32x16 accU = __builtin_amdgcn_mfma_f32_32x32x16_bf16(hf[0], rW2[0], Z, 0, 0, 0);
        #pragma unroll
        for (int s = 1; s < 4; s++)
            accU = __builtin_amdgcn_mfma_f32_32x32x16_bf16(hf[s], rW2[s], accU, 0, 0, 0);
        bf16x8 uf[2] = { pk8(accU, 0), pk8(accU, 1) };

        // ---- P4: V = App @ U -> lane=i', rows=l
        f32x16 accV = __builtin_amdgcn_mfma_f32_32x32x16_bf16(uf[0], rApp[0], Z, 0, 0, 0);
        accV = __builtin_amdgcn_mfma_f32_32x32x16_bf16(uf[1], rApp[1], accV, 0, 0, 0);
        bf16x8 vf[2] = { pk8(accV, 0), pk8(accV, 1) };

        // ---- P5: HD^T = relu(W3 @ V^T + bpp) -> lane=i', rows=d
        bf16x8 hd[4];
        #pragma unroll
        for (int tt = 0; tt < 2; tt++) {
            f32x16 acc = __builtin_amdgcn_mfma_f32_32x32x16_bf16(rW3[tt * 2 + 0], vf[0], Z, 0, 0, 0);
            acc = __builtin_amdgcn_mfma_f32_32x32x16_bf16(rW3[tt * 2 + 1], vf[1], acc, 0, 0, 0);
            #pragma unroll
            for (int st = 0; st < 2; st++) {
                const int g = 2 * tt + st;
                #pragma unroll
                for (int jj = 0; jj < 8; jj++)
                    acc[8 * st + jj] = fmaxf(acc[8 * st + jj] + rBq[g * 2 + (jj >> 2)][jj & 3], 0.f);
                hd[g] = pk8(acc, st);
            }
        }

        // ---- P6: P = HD @ W4  (K=64) -> C lane=c, rows=i'
        f32x16 accP = __builtin_amdgcn_mfma_f32_32x32x16_bf16(hd[0], rW4[0], Z, 0, 0, 0);
        #pragma unroll
        for (int s = 1; s < 4; s++)
            accP = __builtin_amdgcn_mfma_f32_32x32x16_bf16(hd[s], rW4[s], accP, 0, 0, 0);
        bf16x8 pf[2] = { pk8(accP, 0), pk8(accP, 1) };

        // ---- P7: out = A4 @ P + b4 -> C lane=c, rows=i''
        f32x16 accO = __builtin_amdgcn_mfma_f32_32x32x16_bf16(rA4b[0], pf[0], Z, 0, 0, 0);
        accO = __builtin_amdgcn_mfma_f32_32x32x16_bf16(rA4b[1], pf[1], accO, 0, 0, 0);
        if (ln < 3) {
            const long ob = f * NJC;
            #pragma unroll
            for (int r = 0; r < 16; r++) {
                const int row = (r & 3) + 8 * (r >> 2) + 4 * half;
                if (row < J) out[ob + row * 3 + ln] = accO[r] + b4v;
            }
        }
    }
}

// ---------------------------------------------------------------------------
extern "C" void kernel_launch(void* const* d_in, const int* in_sizes, int n_in,
                              void* d_out, int out_size, void* d_ws, size_t ws_size,
                              hipStream_t stream)
{
    const float* x  = (const float*)d_in[0];
    const float* A1 = (const float*)d_in[1];
    const float* W1 = (const float*)d_in[2];
    const float* b1 = (const float*)d_in[3];
    const float* A2 = (const float*)d_in[4];
    const float* W2 = (const float*)d_in[5];
    const float* b2 = (const float*)d_in[6];
    const float* A3 = (const float*)d_in[7];
    const float* W3 = (const float*)d_in[8];
    const float* b3 = (const float*)d_in[9];
    const float* A4 = (const float*)d_in[10];
    const float* W4 = (const float*)d_in[11];
    const float* b4 = (const float*)d_in[12];
    float* out = (float*)d_out;
    __bf16* cw = (__bf16*)d_ws;

    const int NT = in_sizes[0] / NJC;                 // 65536
    const int nblocks = NT / (NWAVE * NFPW);          // 4096

    gcn_precompute<<<1, 256, 0, stream>>>(
        A1, W1, b1, A2, W2, b2, A3, W3, b3, A4, W4, b4, cw);
    gcn_fused<<<nblocks, NTHREADS, 0, stream>>>(x, cw, out);
}